// Round 11
// baseline (204.775 us; speedup 1.0000x reference)
//
#include <hip/hip_runtime.h>
#include <hip/hip_fp16.h>
#include <math.h>
#include <stdint.h>

// VQ via f16x3 split MFMA (32x32x16): dot = (hi.hi + hi.lo + lo.hi) * 2^-20.
// diff = (v2 - 2*dot) + c2 fp32-rounded per np; argmin codes 1..4095, ties -> lowest n.
// R20 = R19 3-ring + REGISTER-LEVEL fragment double-buffer. Per kstep:
// STAGE(k+2) -> vmcnt(6) (proves buf k+1 landed) -> raw s_barrier -> issue ds_reads
// for kstep k+1 into the spare reg buffer (no wait) -> 24 MFMAs on regs read last
// iteration (lgkm wait ~0). The LDS-read latency leaves the critical path.
// (256,1): 512 unified regs/wave (acc 128 + 2x48 frags + misc ~ 280) -> no spill;
// 1 block/CU, each SIMD's lone wave saturates its matrix pipe by ILP (8 indep accs).
// Staged bytes + MFMA order identical to R9-R19 -> bit-exact.

#define M_TOTAL 16384
#define NCODES  4096
#define D_DIM   256

#define OUT_OFF_IDX  (M_TOTAL * D_DIM)
#define OUT_OFF_LOSS (OUT_OFF_IDX + M_TOTAL)

typedef _Float16 half8 __attribute__((ext_vector_type(8)));
typedef float    float16v __attribute__((ext_vector_type(16)));

__device__ __forceinline__ void gload_lds16(const void* g, void* l) {
  __builtin_amdgcn_global_load_lds(
      (const __attribute__((address_space(1))) void*)g,
      (__attribute__((address_space(3))) void*)l, 16, 0, 0);
}

// ---- fused prep: blocks 0..255 = W (pack Bp + c2), 256..1279 = V (pack Vp + v2 + pk init) ----
// Bp element (n,k,plane): panel=n>>5, kstep=k>>4, lhi=(k>>3)&1
//   offset = (panel*16+kstep)*2048 + plane*1024 + lhi*256 + (n&31)*8 + (k&7)   [halfs]
// Vp element (m,k,plane): panel=m>>5, kstep=k>>4, lhi=(k>>3)&1   (tight: fits 16MB d_out)
//   offset = (panel*16+kstep)*1024 + plane*512  + lhi*256 + (m&31)*8 + (k&7)   [halfs]
__global__ __launch_bounds__(256) void prep_kernel(
    const float* __restrict__ V, const float* __restrict__ W,
    _Float16* __restrict__ Vp, _Float16* __restrict__ Bp,
    float* __restrict__ v2, float* __restrict__ c2,
    uint64_t* __restrict__ pk)
{
  __shared__ float T[16 * 264];
  const int t = threadIdx.x;
  const int rloc = t >> 4, seg = t & 15;
  const bool isW = blockIdx.x < 256;
  const int bid2 = isW ? blockIdx.x : (blockIdx.x - 256);
  const int row = bid2 * 16 + rloc;
  const float* X = isW ? W : V;

  if (!isW && bid2 < 64) pk[bid2 * 256 + t] = ~0ULL;   // init argmin array

  const float* src = X + (size_t)row * D_DIM + seg * 16;
  float4 x[4];
#pragma unroll
  for (int u = 0; u < 4; ++u) x[u] = ((const float4*)src)[u];
  union { half8 v; _Float16 e[8]; } uh[2], ul[2];
#pragma unroll
  for (int u = 0; u < 4; ++u) {
    float e4[4] = {x[u].x, x[u].y, x[u].z, x[u].w};
#pragma unroll
    for (int j = 0; j < 4; ++j) {
      const int e = u * 4 + j;
      float s = e4[j] * 1024.0f;            // exact pow2 scale
      _Float16 h = (_Float16)s;             // RN
      uh[e >> 3].e[e & 7] = h;
      ul[e >> 3].e[e & 7] = (_Float16)(s - (float)h);  // RN of exact residual
    }
    *(float4*)&T[rloc * 264 + seg * 16 + u * 4] = x[u];
  }
  if (isW) {
    const int panel = row >> 5, nin = row & 31;
    _Float16* dst = Bp + ((size_t)panel * 16 + seg) * 2048 + nin * 8;
#pragma unroll
    for (int lh = 0; lh < 2; ++lh) {
      *(half8*)(dst + lh * 256)        = uh[lh].v;   // hi plane
      *(half8*)(dst + 1024 + lh * 256) = ul[lh].v;   // lo plane
    }
  } else {
    _Float16* dst = Vp + ((size_t)(row >> 5) * 16 + seg) * 1024 + (row & 31) * 8;
#pragma unroll
    for (int lh = 0; lh < 2; ++lh) {
      *(half8*)(dst + lh * 256)        = uh[lh].v;   // hi plane
      *(half8*)(dst + 512 + lh * 256)  = ul[lh].v;   // lo plane
    }
  }
  __syncthreads();
  // rowsq, numpy pairwise chain order (fadd commutative -> shuffle tree exact)
  const int half = (t >> 3) & 1, j = t & 7;
  const float* tr = &T[rloc * 264 + half * 128 + j];
  float r = __fmul_rn(tr[0], tr[0]);
#pragma unroll
  for (int i = 1; i < 16; ++i) { float e = tr[8 * i]; r = __fadd_rn(r, __fmul_rn(e, e)); }
  r = __fadd_rn(r, __shfl_xor(r, 1));
  r = __fadd_rn(r, __shfl_xor(r, 2));
  r = __fadd_rn(r, __shfl_xor(r, 4));
  r = __fadd_rn(r, __shfl_xor(r, 8));   // pw(0:128) + pw(128:256)
  if ((t & 15) == 0) { if (isW) c2[row] = r; else v2[row] = r; }
}

// ---- main: block 256m x 128n, 4 waves 2x2, wave tile 128m x 64n (Tm=4, Tn=2) ----
// LDS: 3-buffer ring, 24 KB each (A 16K at [0,16K), B 8K at [16K,24K) per buf).
// red2 at 73728. Epilogue wbuf reuses [0,33792).
__global__ __launch_bounds__(256, 1) void vq_mfma_kernel(
    const _Float16* __restrict__ Vp, const _Float16* __restrict__ Bp,
    const float* __restrict__ v2, const float* __restrict__ c2,
    uint64_t* __restrict__ pk)
{
  __shared__ __align__(16) char smem[77824];
  uint64_t* red2 = (uint64_t*)(smem + 73728);

  const int tid  = threadIdx.x;
  const int lane = tid & 63;
  const int wave = tid >> 6;           // 0..3
  const int wr = wave >> 1, wc = wave & 1;
  const int l31 = lane & 31, lhi = lane >> 5;

  const int bid = blockIdx.x;
  // L2-residency swizzle: XCD (bid&7) owns mblks {xcd*8..xcd*8+7} (2 MB Vp slice);
  // pblks swept outer -> A loads are L2 hits after warmup.
  const int xcd  = bid & 7;
  const int seq  = bid >> 3;            // 0..255
  const int mblk = xcd * 8 + (seq & 7); // 0..63
  const int pblk = seq >> 3;            // 0..31 (128 n-cols each)
  const int m0 = mblk * 256;
  const int n0 = pblk * 128;

  // ---- staging assignment: 24 x 1KB chunks per kstep, 6 per wave ----
  // chunk c<16: A (panel p=c>>1, plane pl=c&1), byte src ((mblk*8+p)*16+k)*2048 + pl*1024
  // chunk c>=16: B (b=c-16, panel pn=b>>1, pl=b&1), src ((pblk*4+pn)*16+k)*4096 + pl*2048
  // dst = c*1024 (A at [0,16K), B at [16K,24K) within each ring buffer).
  const char* gsrc[6];
  int gstr[6], dstOff[6];
#pragma unroll
  for (int j = 0; j < 6; ++j) {
    const int c = wave * 6 + j;
    dstOff[j] = c * 1024;
    if (c < 16) {
      const int p = c >> 1, pl = c & 1;
      gsrc[j] = (const char*)Vp + ((size_t)(mblk * 8 + p) * 16) * 2048 + pl * 1024 + lane * 16;
      gstr[j] = 2048;
    } else {
      const int b = c - 16, pn = b >> 1, pl = b & 1;
      gsrc[j] = (const char*)Bp + ((size_t)(pblk * 4 + pn) * 16) * 4096 + pl * 2048 + lane * 16;
      gstr[j] = 4096;
    }
  }

  auto STAGE = [&](int kb) {                     // stages next kstep at gsrc cursor
#pragma unroll
    for (int j = 0; j < 6; ++j) {
      gload_lds16(gsrc[j], smem + kb * 24576 + dstOff[j]);
      gsrc[j] += gstr[j];
    }
  };

  float16v acc[4][2];
#pragma unroll
  for (int mb = 0; mb < 4; ++mb)
#pragma unroll
    for (int nb = 0; nb < 2; ++nb) acc[mb][nb] = (float16v)0.0f;

  // register fragment double-buffer
  half8 ah[2][4], al[2][4], bh[2][2], bl[2][2];

  auto LDREAD = [&](int kst, int pb) {           // issue frag reads for kstep kst
    const char* Ab = smem + (kst % 3) * 24576 + (wr * 4) * 2048 + lane * 16;
    const char* Bb = smem + (kst % 3) * 24576 + 16384 + (wc * 2) * 2048 + lane * 16;
#pragma unroll
    for (int mb = 0; mb < 4; ++mb) {
      ah[pb][mb] = *(const half8*)(Ab + mb * 2048);
      al[pb][mb] = *(const half8*)(Ab + mb * 2048 + 1024);
    }
#pragma unroll
    for (int nb = 0; nb < 2; ++nb) {
      bh[pb][nb] = *(const half8*)(Bb + nb * 2048);
      bl[pb][nb] = *(const half8*)(Bb + nb * 2048 + 1024);
    }
  };

  STAGE(0);                                      // kstep 0 -> buf 0   (6 in flight)
  STAGE(1);                                      // kstep 1 -> buf 1   (12 in flight)
  asm volatile("s_waitcnt vmcnt(6)" ::: "memory");   // buf 0 landed
  __builtin_amdgcn_sched_barrier(0);
  __builtin_amdgcn_s_barrier();                  // buf 0 visible to all waves
  __builtin_amdgcn_sched_barrier(0);
  LDREAD(0, 0);                                  // frag(0) -> regbuf 0 (no wait)
  __builtin_amdgcn_sched_barrier(0);

#pragma unroll
  for (int k = 0; k < 16; ++k) {
    const int pb = k & 1;
    if (k <= 13) STAGE((k + 2) % 3);             // issue k+2 (ring slot freed at k-1)
    // counted wait: after the stage issue, outstanding = {k-1 batch, k batch};
    // vmcnt(6) drains the k-1 batch -> buf k+1 LANDED. Never 0 mid-loop (T4).
    if (k <= 13)      asm volatile("s_waitcnt vmcnt(6)" ::: "memory");
    else if (k == 14) asm volatile("s_waitcnt vmcnt(0)" ::: "memory");
    if (k < 15) {
      __builtin_amdgcn_sched_barrier(0);
      __builtin_amdgcn_s_barrier();              // buf k+1 visible to all waves
      __builtin_amdgcn_sched_barrier(0);
      LDREAD(k + 1, pb ^ 1);                     // issue only; consumed next iter
      __builtin_amdgcn_sched_barrier(0);         // pin reads before the MFMAs
    }
    // product-major, per-acc order identical to R9-R19 (bit-exact):
    // hi.hi, hi.lo, lo.hi within each kstep, ksteps ascending.
    // Operands in regbuf pb were read LAST iteration -> lgkm wait ~0.
#pragma unroll
    for (int nb = 0; nb < 2; ++nb)
#pragma unroll
      for (int mb = 0; mb < 4; ++mb)
        acc[mb][nb] = __builtin_amdgcn_mfma_f32_32x32x16_f16(ah[pb][mb], bh[pb][nb], acc[mb][nb], 0, 0, 0);
#pragma unroll
    for (int nb = 0; nb < 2; ++nb)
#pragma unroll
      for (int mb = 0; mb < 4; ++mb)
        acc[mb][nb] = __builtin_amdgcn_mfma_f32_32x32x16_f16(ah[pb][mb], bl[pb][nb], acc[mb][nb], 0, 0, 0);
#pragma unroll
    for (int nb = 0; nb < 2; ++nb)
#pragma unroll
      for (int mb = 0; mb < 4; ++mb)
        acc[mb][nb] = __builtin_amdgcn_mfma_f32_32x32x16_f16(al[pb][mb], bh[pb][nb], acc[mb][nb], 0, 0, 0);
  }
  __syncthreads();                               // drain before LDS reuse as wbuf

  // ---- epilogue: diff = (v2 - 2*dot) + c2 (np order), argmin, tie -> lowest n ----
  float c2r[2];
#pragma unroll
  for (int nb = 0; nb < 2; ++nb) c2r[nb] = c2[n0 + wc * 64 + nb * 32 + l31];

  uint64_t* wbuf = (uint64_t*)smem + wave * 1056;   // 32 rows x 33 u64, wave-private

#pragma unroll
  for (int mb = 0; mb < 4; ++mb) {
#pragma unroll
    for (int r = 0; r < 16; ++r) {
      const int rowin = (r & 3) + 8 * (r >> 2) + 4 * lhi;
      const float v2m = v2[m0 + wr * 128 + mb * 32 + rowin];
      uint64_t b = ~0ULL;
#pragma unroll
      for (int nb = 0; nb < 2; ++nb) {
        const int n = n0 + wc * 64 + nb * 32 + l31;
        float dot = acc[mb][nb][r] * 0x1p-20f;            // exact pow2 unscale
        float dd  = __fadd_rn(__fsub_rn(v2m, 2.0f * dot), c2r[nb]);
        if (n == 0) dd = INFINITY;                        // exclude code 0
        uint64_t p = ((uint64_t)__float_as_uint(dd) << 32) | (uint32_t)n;
        if (p < b) b = p;                                 // dd>0 -> bits monotonic
      }
      wbuf[(r * 2 + lhi) * 33 + l31] = b;
    }
    {
      const int f = lane >> 1, hf = lane & 1;
      const uint64_t* rp = wbuf + f * 33 + hf * 16;
      uint64_t m = rp[0];
#pragma unroll
      for (int i = 1; i < 16; ++i) { uint64_t v = rp[i]; if (v < m) m = v; }
      uint64_t o = __shfl_xor((unsigned long long)m, 1);
      if (o < m) m = o;
      if (hf == 0) {
        const int r_ = f >> 1, lh2 = f & 1;
        const int rowin = (r_ & 3) + 8 * (r_ >> 2) + 4 * lh2;
        red2[(wr * 128 + mb * 32 + rowin) * 2 + wc] = m;
      }
    }
  }
  __syncthreads();

  uint64_t a0 = red2[tid * 2], a1 = red2[tid * 2 + 1];
  atomicMin((unsigned long long*)&pk[m0 + tid], (unsigned long long)(a0 < a1 ? a0 : a1));
}

// ---- gather: one wave per query, no barriers ----
__global__ __launch_bounds__(256) void gather_kernel(
    const float* __restrict__ V, const float* __restrict__ W,
    const uint64_t* __restrict__ pk,
    float* __restrict__ out, float* __restrict__ outIdx,
    float* __restrict__ lossPartial)
{
  const int q = blockIdx.x * 4 + (threadIdx.x >> 6);
  const int l = threadIdx.x & 63;
  const uint64_t b = pk[q];             // wave-uniform broadcast load
  float4 vv = *(const float4*)(V + (size_t)q * D_DIM + l * 4);
  const float inv = 0.00390625f;
  bool ne = (vv.x != inv) | (vv.y != inv) | (vv.z != inv) | (vv.w != inv);
  const int idx = __ballot(ne) ? (int)(uint32_t)b : 0;
  float4 o4 = *(const float4*)(W + (size_t)idx * D_DIM + l * 4);
  *(float4*)(out + (size_t)q * D_DIM + l * 4) = o4;
  if (l == 0) outIdx[q] = (float)idx;
  float dx = o4.x - vv.x, dy = o4.y - vv.y, dz = o4.z - vv.z, dw = o4.w - vv.w;
  float s = dx * dx + dy * dy + dz * dz + dw * dw;
#pragma unroll
  for (int off = 32; off; off >>= 1) s += __shfl_xor(s, off);
  if (l == 0) lossPartial[q] = s;
}

__global__ __launch_bounds__(256) void finalize_kernel(
    const float* __restrict__ lossPartial, float* __restrict__ out)
{
  const int t = threadIdx.x;
  __shared__ float red[256];
  float s = 0.0f;
  for (int i = t; i < M_TOTAL; i += 256) s += lossPartial[i];
  red[t] = s;
  __syncthreads();
  for (int st = 128; st > 0; st >>= 1) {
    if (t < st) red[t] += red[t + st];
    __syncthreads();
  }
  if (t == 0) {
    out[0] = (float)((double)red[0] / (double)(M_TOTAL * D_DIM));  // loss
    out[1] = 0.0f;                                                 // used
  }
}

extern "C" void kernel_launch(void* const* d_in, const int* in_sizes, int n_in,
                              void* d_out, int out_size, void* d_ws, size_t ws_size,
                              hipStream_t stream) {
  const float* V = (const float*)d_in[0];   // 16384 x 256
  const float* W = (const float*)d_in[1];   // 4096 x 256
  float* out = (float*)d_out;

  // Packed V fragments live in d_out (exactly 16384*256*4 bytes); gather overwrites later.
  _Float16* Vp = (_Float16*)d_out;

  char* ws = (char*)d_ws;
  _Float16* Bp  = (_Float16*)(ws);                        // packed W frags: 8 MB region
  float*    c2  = (float*)(ws + 8388608);                 // 16 KB
  float*    v2  = (float*)(ws + 8388608 + 16384);         // 64 KB
  uint64_t* pk  = (uint64_t*)(ws + 8388608 + 16384 + 65536);   // 16384 u64 = 128 KB
  float* lossPartial = (float*)(ws + 8388608 + 16384 + 65536 + 131072);  // 64 KB

  prep_kernel<<<1280, 256, 0, stream>>>(V, W, Vp, Bp, v2, c2, pk);
  vq_mfma_kernel<<<2048, 256, 0, stream>>>(Vp, Bp, v2, c2, pk);
  gather_kernel<<<M_TOTAL / 4, 256, 0, stream>>>(V, W, pk, out, out + OUT_OFF_IDX, lossPartial);
  finalize_kernel<<<1, 256, 0, stream>>>(lossPartial, out + OUT_OFF_LOSS);
}

// Round 12
// 192.474 us; speedup vs baseline: 1.0639x; 1.0639x over previous
//
#include <hip/hip_runtime.h>
#include <hip/hip_fp16.h>
#include <math.h>
#include <stdint.h>

// VQ via f16x3 split MFMA (32x32x16): dot = (hi.hi + hi.lo + lo.hi) * 2^-20.
// diff = (v2 - 2*dot) + c2 fp32-rounded per np; argmin codes 1..4095, ties -> lowest n.
// R21 = R16 geometry + R19 counted-vmcnt 3-ring + 3-SUBPHASE fine interleave w/ setprio.
// Per kstep: P1 {read ah,bh | stage 2 chunks | lgkm0 | prio1 8xMFMA_hh prio0}
//            P2 {read bl    | stage 2 chunks | lgkm0 | prio1 8xMFMA_hl prio0}
//            P3 {read al    | stage 2 chunks | lgkm0 | prio1 8xMFMA_lh prio0}
// then counted vmcnt(6) + ONE raw barrier. Pinned with sched_barrier(0) (rule #18).
// The pinned read/MFMA role-split gives the co-resident block's waves the SIMD
// during read windows (T5's required regime). Block 256m x 128n, 4 waves 2x2,
// (256,2), 2 blocks/CU. Staged bytes + MFMA order identical -> bit-exact vs R9-R20.

#define M_TOTAL 16384
#define NCODES  4096
#define D_DIM   256

#define OUT_OFF_IDX  (M_TOTAL * D_DIM)
#define OUT_OFF_LOSS (OUT_OFF_IDX + M_TOTAL)

typedef _Float16 half8 __attribute__((ext_vector_type(8)));
typedef float    float16v __attribute__((ext_vector_type(16)));

__device__ __forceinline__ void gload_lds16(const void* g, void* l) {
  __builtin_amdgcn_global_load_lds(
      (const __attribute__((address_space(1))) void*)g,
      (__attribute__((address_space(3))) void*)l, 16, 0, 0);
}

// ---- fused prep: blocks 0..255 = W (pack Bp + c2), 256..1279 = V (pack Vp + v2 + pk init) ----
// Bp element (n,k,plane): panel=n>>5, kstep=k>>4, lhi=(k>>3)&1
//   offset = (panel*16+kstep)*2048 + plane*1024 + lhi*256 + (n&31)*8 + (k&7)   [halfs]
// Vp element (m,k,plane): panel=m>>5, kstep=k>>4, lhi=(k>>3)&1   (tight: fits 16MB d_out)
//   offset = (panel*16+kstep)*1024 + plane*512  + lhi*256 + (m&31)*8 + (k&7)   [halfs]
__global__ __launch_bounds__(256) void prep_kernel(
    const float* __restrict__ V, const float* __restrict__ W,
    _Float16* __restrict__ Vp, _Float16* __restrict__ Bp,
    float* __restrict__ v2, float* __restrict__ c2,
    uint64_t* __restrict__ pk)
{
  __shared__ float T[16 * 264];
  const int t = threadIdx.x;
  const int rloc = t >> 4, seg = t & 15;
  const bool isW = blockIdx.x < 256;
  const int bid2 = isW ? blockIdx.x : (blockIdx.x - 256);
  const int row = bid2 * 16 + rloc;
  const float* X = isW ? W : V;

  if (!isW && bid2 < 64) pk[bid2 * 256 + t] = ~0ULL;   // init argmin array

  const float* src = X + (size_t)row * D_DIM + seg * 16;
  float4 x[4];
#pragma unroll
  for (int u = 0; u < 4; ++u) x[u] = ((const float4*)src)[u];
  union { half8 v; _Float16 e[8]; } uh[2], ul[2];
#pragma unroll
  for (int u = 0; u < 4; ++u) {
    float e4[4] = {x[u].x, x[u].y, x[u].z, x[u].w};
#pragma unroll
    for (int j = 0; j < 4; ++j) {
      const int e = u * 4 + j;
      float s = e4[j] * 1024.0f;            // exact pow2 scale
      _Float16 h = (_Float16)s;             // RN
      uh[e >> 3].e[e & 7] = h;
      ul[e >> 3].e[e & 7] = (_Float16)(s - (float)h);  // RN of exact residual
    }
    *(float4*)&T[rloc * 264 + seg * 16 + u * 4] = x[u];
  }
  if (isW) {
    const int panel = row >> 5, nin = row & 31;
    _Float16* dst = Bp + ((size_t)panel * 16 + seg) * 2048 + nin * 8;
#pragma unroll
    for (int lh = 0; lh < 2; ++lh) {
      *(half8*)(dst + lh * 256)        = uh[lh].v;   // hi plane
      *(half8*)(dst + 1024 + lh * 256) = ul[lh].v;   // lo plane
    }
  } else {
    _Float16* dst = Vp + ((size_t)(row >> 5) * 16 + seg) * 1024 + (row & 31) * 8;
#pragma unroll
    for (int lh = 0; lh < 2; ++lh) {
      *(half8*)(dst + lh * 256)        = uh[lh].v;   // hi plane
      *(half8*)(dst + 512 + lh * 256)  = ul[lh].v;   // lo plane
    }
  }
  __syncthreads();
  // rowsq, numpy pairwise chain order (fadd commutative -> shuffle tree exact)
  const int half = (t >> 3) & 1, j = t & 7;
  const float* tr = &T[rloc * 264 + half * 128 + j];
  float r = __fmul_rn(tr[0], tr[0]);
#pragma unroll
  for (int i = 1; i < 16; ++i) { float e = tr[8 * i]; r = __fadd_rn(r, __fmul_rn(e, e)); }
  r = __fadd_rn(r, __shfl_xor(r, 1));
  r = __fadd_rn(r, __shfl_xor(r, 2));
  r = __fadd_rn(r, __shfl_xor(r, 4));
  r = __fadd_rn(r, __shfl_xor(r, 8));   // pw(0:128) + pw(128:256)
  if ((t & 15) == 0) { if (isW) c2[row] = r; else v2[row] = r; }
}

// ---- main: block 256m x 128n, 4 waves 2x2, wave tile 128m x 64n (Tm=4, Tn=2) ----
// LDS: 3-buffer ring, 24 KB each (A 16K at [0,16K), B 8K at [16K,24K) per buf).
// red2 at 73728. Epilogue wbuf reuses [0,33792).
__global__ __launch_bounds__(256, 2) void vq_mfma_kernel(
    const _Float16* __restrict__ Vp, const _Float16* __restrict__ Bp,
    const float* __restrict__ v2, const float* __restrict__ c2,
    uint64_t* __restrict__ pk)
{
  __shared__ __align__(16) char smem[77824];
  uint64_t* red2 = (uint64_t*)(smem + 73728);

  const int tid  = threadIdx.x;
  const int lane = tid & 63;
  const int wave = tid >> 6;           // 0..3
  const int wr = wave >> 1, wc = wave & 1;
  const int l31 = lane & 31, lhi = lane >> 5;

  const int bid = blockIdx.x;
  // L2-residency swizzle: XCD (bid&7) owns mblks {xcd*8..xcd*8+7} (2 MB Vp slice);
  // pblks swept outer -> A loads are L2 hits after warmup.
  const int xcd  = bid & 7;
  const int seq  = bid >> 3;            // 0..255
  const int mblk = xcd * 8 + (seq & 7); // 0..63
  const int pblk = seq >> 3;            // 0..31 (128 n-cols each)
  const int m0 = mblk * 256;
  const int n0 = pblk * 128;

  // ---- staging assignment: 24 x 1KB chunks per kstep, 6 per wave ----
  // chunk c<16: A (panel p=c>>1, plane pl=c&1), byte src ((mblk*8+p)*16+k)*2048 + pl*1024
  // chunk c>=16: B (b=c-16, panel pn=b>>1, pl=b&1), src ((pblk*4+pn)*16+k)*4096 + pl*2048
  // dst = c*1024 (A at [0,16K), B at [16K,24K) within each ring buffer).
  const char* gsrc[6];
  int gstr[6], dstOff[6];
#pragma unroll
  for (int j = 0; j < 6; ++j) {
    const int c = wave * 6 + j;
    dstOff[j] = c * 1024;
    if (c < 16) {
      const int p = c >> 1, pl = c & 1;
      gsrc[j] = (const char*)Vp + ((size_t)(mblk * 8 + p) * 16) * 2048 + pl * 1024 + lane * 16;
      gstr[j] = 2048;
    } else {
      const int b = c - 16, pn = b >> 1, pl = b & 1;
      gsrc[j] = (const char*)Bp + ((size_t)(pblk * 4 + pn) * 16) * 4096 + pl * 2048 + lane * 16;
      gstr[j] = 4096;
    }
  }

  auto STAGE2 = [&](int kst, int j0) {           // 2 chunks of kstep kst's batch
#pragma unroll
    for (int j = j0; j < j0 + 2; ++j) {
      gload_lds16(gsrc[j], smem + (kst % 3) * 24576 + dstOff[j]);
      gsrc[j] += gstr[j];
    }
  };
  auto STAGEFULL = [&](int kst) {
#pragma unroll
    for (int j = 0; j < 6; ++j) {
      gload_lds16(gsrc[j], smem + (kst % 3) * 24576 + dstOff[j]);
      gsrc[j] += gstr[j];
    }
  };

  float16v acc[4][2];
#pragma unroll
  for (int mb = 0; mb < 4; ++mb)
#pragma unroll
    for (int nb = 0; nb < 2; ++nb) acc[mb][nb] = (float16v)0.0f;

  STAGEFULL(0);                                  // kstep 0 -> buf 0   (6 in flight)
  STAGEFULL(1);                                  // kstep 1 -> buf 1   (12 in flight)
  asm volatile("s_waitcnt vmcnt(6)" ::: "memory");   // buf 0 landed
  __builtin_amdgcn_sched_barrier(0);
  __builtin_amdgcn_s_barrier();                  // buf 0 visible to all waves
  __builtin_amdgcn_sched_barrier(0);

#pragma unroll
  for (int k = 0; k < 16; ++k) {
    const char* Ab = smem + (k % 3) * 24576 + (wr * 4) * 2048 + lane * 16;
    const char* Bb = smem + (k % 3) * 24576 + 16384 + (wc * 2) * 2048 + lane * 16;
    half8 ah[4], al[4], bh[2], bl[2];

    // ---- P1: reads for hh | 2 staging chunks | 8 MFMA hh ----
#pragma unroll
    for (int mb = 0; mb < 4; ++mb) ah[mb] = *(const half8*)(Ab + mb * 2048);
#pragma unroll
    for (int nb = 0; nb < 2; ++nb) bh[nb] = *(const half8*)(Bb + nb * 2048);
    if (k <= 13) STAGE2(k + 2, 0);
    asm volatile("s_waitcnt lgkmcnt(0)" ::: "memory");
    __builtin_amdgcn_sched_barrier(0);           // rule #18: MFMAs stay below
    __builtin_amdgcn_s_setprio(1);
#pragma unroll
    for (int nb = 0; nb < 2; ++nb)
#pragma unroll
      for (int mb = 0; mb < 4; ++mb)
        acc[mb][nb] = __builtin_amdgcn_mfma_f32_32x32x16_f16(ah[mb], bh[nb], acc[mb][nb], 0, 0, 0);
    __builtin_amdgcn_s_setprio(0);
    __builtin_amdgcn_sched_barrier(0);

    // ---- P2: reads bl | 2 staging chunks | 8 MFMA hl ----
#pragma unroll
    for (int nb = 0; nb < 2; ++nb) bl[nb] = *(const half8*)(Bb + nb * 2048 + 1024);
    if (k <= 13) STAGE2(k + 2, 2);
    asm volatile("s_waitcnt lgkmcnt(0)" ::: "memory");
    __builtin_amdgcn_sched_barrier(0);
    __builtin_amdgcn_s_setprio(1);
#pragma unroll
    for (int nb = 0; nb < 2; ++nb)
#pragma unroll
      for (int mb = 0; mb < 4; ++mb)
        acc[mb][nb] = __builtin_amdgcn_mfma_f32_32x32x16_f16(ah[mb], bl[nb], acc[mb][nb], 0, 0, 0);
    __builtin_amdgcn_s_setprio(0);
    __builtin_amdgcn_sched_barrier(0);

    // ---- P3: reads al | 2 staging chunks | 8 MFMA lh ----
#pragma unroll
    for (int mb = 0; mb < 4; ++mb) al[mb] = *(const half8*)(Ab + mb * 2048 + 1024);
    if (k <= 13) STAGE2(k + 2, 4);
    asm volatile("s_waitcnt lgkmcnt(0)" ::: "memory");
    __builtin_amdgcn_sched_barrier(0);
    __builtin_amdgcn_s_setprio(1);
#pragma unroll
    for (int nb = 0; nb < 2; ++nb)
#pragma unroll
      for (int mb = 0; mb < 4; ++mb)
        acc[mb][nb] = __builtin_amdgcn_mfma_f32_32x32x16_f16(al[mb], bh[nb], acc[mb][nb], 0, 0, 0);
    __builtin_amdgcn_s_setprio(0);
    __builtin_amdgcn_sched_barrier(0);

    // ---- end of kstep: counted wait (T4, never 0 mid-loop) + ONE raw barrier ----
    // outstanding = batch k+1 (6, issued during kstep k-1) + batch k+2 (6, just
    // issued); vmcnt(6) drains k+1 -> buf k+1 landed for next iteration.
    if (k <= 13)      asm volatile("s_waitcnt vmcnt(6)" ::: "memory");
    else if (k == 14) asm volatile("s_waitcnt vmcnt(0)" ::: "memory");
    if (k < 15) {
      __builtin_amdgcn_sched_barrier(0);
      __builtin_amdgcn_s_barrier();              // buf k+1 visible to all waves
      __builtin_amdgcn_sched_barrier(0);
    }
  }
  __syncthreads();                               // drain before LDS reuse as wbuf

  // ---- epilogue: diff = (v2 - 2*dot) + c2 (np order), argmin, tie -> lowest n ----
  float c2r[2];
#pragma unroll
  for (int nb = 0; nb < 2; ++nb) c2r[nb] = c2[n0 + wc * 64 + nb * 32 + l31];

  uint64_t* wbuf = (uint64_t*)smem + wave * 1056;   // 32 rows x 33 u64, wave-private

#pragma unroll
  for (int mb = 0; mb < 4; ++mb) {
#pragma unroll
    for (int r = 0; r < 16; ++r) {
      const int rowin = (r & 3) + 8 * (r >> 2) + 4 * lhi;
      const float v2m = v2[m0 + wr * 128 + mb * 32 + rowin];
      uint64_t b = ~0ULL;
#pragma unroll
      for (int nb = 0; nb < 2; ++nb) {
        const int n = n0 + wc * 64 + nb * 32 + l31;
        float dot = acc[mb][nb][r] * 0x1p-20f;            // exact pow2 unscale
        float dd  = __fadd_rn(__fsub_rn(v2m, 2.0f * dot), c2r[nb]);
        if (n == 0) dd = INFINITY;                        // exclude code 0
        uint64_t p = ((uint64_t)__float_as_uint(dd) << 32) | (uint32_t)n;
        if (p < b) b = p;                                 // dd>0 -> bits monotonic
      }
      wbuf[(r * 2 + lhi) * 33 + l31] = b;
    }
    {
      const int f = lane >> 1, hf = lane & 1;
      const uint64_t* rp = wbuf + f * 33 + hf * 16;
      uint64_t m = rp[0];
#pragma unroll
      for (int i = 1; i < 16; ++i) { uint64_t v = rp[i]; if (v < m) m = v; }
      uint64_t o = __shfl_xor((unsigned long long)m, 1);
      if (o < m) m = o;
      if (hf == 0) {
        const int r_ = f >> 1, lh2 = f & 1;
        const int rowin = (r_ & 3) + 8 * (r_ >> 2) + 4 * lh2;
        red2[(wr * 128 + mb * 32 + rowin) * 2 + wc] = m;
      }
    }
  }
  __syncthreads();

  uint64_t a0 = red2[tid * 2], a1 = red2[tid * 2 + 1];
  atomicMin((unsigned long long*)&pk[m0 + tid], (unsigned long long)(a0 < a1 ? a0 : a1));
}

// ---- gather: one wave per query, no barriers ----
__global__ __launch_bounds__(256) void gather_kernel(
    const float* __restrict__ V, const float* __restrict__ W,
    const uint64_t* __restrict__ pk,
    float* __restrict__ out, float* __restrict__ outIdx,
    float* __restrict__ lossPartial)
{
  const int q = blockIdx.x * 4 + (threadIdx.x >> 6);
  const int l = threadIdx.x & 63;
  const uint64_t b = pk[q];             // wave-uniform broadcast load
  float4 vv = *(const float4*)(V + (size_t)q * D_DIM + l * 4);
  const float inv = 0.00390625f;
  bool ne = (vv.x != inv) | (vv.y != inv) | (vv.z != inv) | (vv.w != inv);
  const int idx = __ballot(ne) ? (int)(uint32_t)b : 0;
  float4 o4 = *(const float4*)(W + (size_t)idx * D_DIM + l * 4);
  *(float4*)(out + (size_t)q * D_DIM + l * 4) = o4;
  if (l == 0) outIdx[q] = (float)idx;
  float dx = o4.x - vv.x, dy = o4.y - vv.y, dz = o4.z - vv.z, dw = o4.w - vv.w;
  float s = dx * dx + dy * dy + dz * dz + dw * dw;
#pragma unroll
  for (int off = 32; off; off >>= 1) s += __shfl_xor(s, off);
  if (l == 0) lossPartial[q] = s;
}

__global__ __launch_bounds__(256) void finalize_kernel(
    const float* __restrict__ lossPartial, float* __restrict__ out)
{
  const int t = threadIdx.x;
  __shared__ float red[256];
  float s = 0.0f;
  for (int i = t; i < M_TOTAL; i += 256) s += lossPartial[i];
  red[t] = s;
  __syncthreads();
  for (int st = 128; st > 0; st >>= 1) {
    if (t < st) red[t] += red[t + st];
    __syncthreads();
  }
  if (t == 0) {
    out[0] = (float)((double)red[0] / (double)(M_TOTAL * D_DIM));  // loss
    out[1] = 0.0f;                                                 // used
  }
}

extern "C" void kernel_launch(void* const* d_in, const int* in_sizes, int n_in,
                              void* d_out, int out_size, void* d_ws, size_t ws_size,
                              hipStream_t stream) {
  const float* V = (const float*)d_in[0];   // 16384 x 256
  const float* W = (const float*)d_in[1];   // 4096 x 256
  float* out = (float*)d_out;

  // Packed V fragments live in d_out (exactly 16384*256*4 bytes); gather overwrites later.
  _Float16* Vp = (_Float16*)d_out;

  char* ws = (char*)d_ws;
  _Float16* Bp  = (_Float16*)(ws);                        // packed W frags: 8 MB region
  float*    c2  = (float*)(ws + 8388608);                 // 16 KB
  float*    v2  = (float*)(ws + 8388608 + 16384);         // 64 KB
  uint64_t* pk  = (uint64_t*)(ws + 8388608 + 16384 + 65536);   // 16384 u64 = 128 KB
  float* lossPartial = (float*)(ws + 8388608 + 16384 + 65536 + 131072);  // 64 KB

  prep_kernel<<<1280, 256, 0, stream>>>(V, W, Vp, Bp, v2, c2, pk);
  vq_mfma_kernel<<<2048, 256, 0, stream>>>(Vp, Bp, v2, c2, pk);
  gather_kernel<<<M_TOTAL / 4, 256, 0, stream>>>(V, W, pk, out, out + OUT_OFF_IDX, lossPartial);
  finalize_kernel<<<1, 256, 0, stream>>>(lossPartial, out + OUT_OFF_LOSS);
}